// Round 17
// baseline (734.718 us; speedup 1.0000x reference)
//
#include <hip/hip_runtime.h>
#include <hip/hip_bf16.h>
#include <stdint.h>

#define SEQ 2048
#define EMB 1024

typedef __attribute__((ext_vector_type(4))) float f32x4;
typedef __attribute__((ext_vector_type(8))) __bf16 bf16x8v;
typedef __attribute__((ext_vector_type(8))) unsigned short u16x8;
typedef __attribute__((ext_vector_type(4))) unsigned short u16x4;

static __device__ __forceinline__ float bf2f(unsigned short u){
  union { unsigned int i; float f; } v; v.i = ((unsigned int)u) << 16; return v.f;
}
static __device__ __forceinline__ unsigned short f2bf(float f){
  union { float f; unsigned int i; } v; v.f = f;
  unsigned int r = v.i + 0x7FFFu + ((v.i >> 16) & 1u);
  return (unsigned short)(r >> 16);
}

static __device__ __forceinline__ void gload16(const unsigned short* g, unsigned short* l){
  __builtin_amdgcn_global_load_lds(
      (__attribute__((address_space(1))) unsigned int*)(g),
      (__attribute__((address_space(3))) unsigned int*)(l), 16, 0, 0);
}

// XCD-aware tile swizzle (valid when nwg % 8 == 0)
static __device__ __forceinline__ int xcd_swz(int bid, int nwg){
  int q = nwg >> 3;
  return (bid & 7) * q + (bid >> 3);
}

// ---------------- converters ----------------
__global__ __launch_bounds__(256) void k_cvt_bf16(const float* __restrict__ in,
                                                  unsigned short* __restrict__ out, long n4){
  long i = (long)blockIdx.x * 256 + threadIdx.x;
  if (i >= n4) return;
  float4 v = ((const float4*)in)[i];
  u16x4 o; o.x = f2bf(v.x); o.y = f2bf(v.y); o.z = f2bf(v.z); o.w = f2bf(v.w);
  ((u16x4*)out)[i] = o;
}

__global__ __launch_bounds__(256) void k_build_wcat(
    const float* __restrict__ w0, const float* __restrict__ w1,
    const float* __restrict__ w2, const float* __restrict__ w3,
    const float* __restrict__ w4, const float* __restrict__ w5,
    unsigned short* __restrict__ wcat){
  long i = (long)blockIdx.x * 256 + threadIdx.x;
  long g = i * 4;
  int m = (int)(g >> 21);
  const float* src = (m==0)?w0:(m==1)?w1:(m==2)?w2:(m==3)?w3:(m==4)?w4:w5;
  long loc = g & ((1L<<21)-1);
  float4 v = *(const float4*)&src[loc];
  u16x4 o; o.x=f2bf(v.x); o.y=f2bf(v.y); o.z=f2bf(v.z); o.w=f2bf(v.w);
  *(u16x4*)&wcat[g] = o;
}

__global__ __launch_bounds__(256) void k_build_bcat(
    const float* b0, const float* b1, const float* b2,
    const float* b3, const float* b4, const float* b5, float* __restrict__ bcat){
  int i = blockIdx.x * 256 + threadIdx.x;
  int m = i >> 11;
  const float* src = (m==0)?b0:(m==1)?b1:(m==2)?b2:(m==3)?b3:(m==4)?b4:b5;
  bcat[i] = src[i & 2047];
}

#define M_LIN   0
#define M_SCORE 1
#define M_PV    2
#define M_OUT   3

// ====== 256xBN GEMM (C = A @ B^T), 512 thr / 8 waves (2M x 4N), BK=64 ======
// SCHED=0: r10 3-gate read-ahead rotation (best for LIN: 100us, MfmaUtil 44%).
// SCHED=1: r15 2-gate dual-A, 64 MFMA between barriers (best for SCORE/PV/OUT:
//   total -30us vs SCHED=0 on those dispatches; worse on LIN 100->113).
// Both ledgers multi-replay-validated (r10..r15). WAR: every staged region's
// last LDS read is >=2 barriers before its next stage-issue.
// NMAJ=1 (LIN/OUT): N-major tiles -> B-panel L2-resident (FETCH 205->110MB).
// NMAJ=0 (SCORE/PV): M-major (rs atomics XCD-local).
// M_LIN + vtp: V-range tiles write VT[head][e][t] directly (fused transpose).
// M_SCORE: E=exp(s*tfidf/32) + atomic row-sums into rs.  M_PV: /rs then AO.
template<int MODE, int BN, int NMAJ, int SCHED>
__global__ __launch_bounds__(512, 2)
void gemm4p(const unsigned short* __restrict__ A_,
            const unsigned short* __restrict__ B_,
            unsigned short* __restrict__ Cb, float* __restrict__ Cf,
            const float* __restrict__ bias, const float* __restrict__ tfb,
            unsigned short* __restrict__ vtp, int nbl,
            int ld, int ldc, int tilesA, int accflag)
{
  constexpr int KD  = (MODE==M_PV || MODE==M_OUT) ? 2048 : 1024;
  constexpr int NT  = KD/64;
  constexpr int NREP= BN/64;      // 4 or 2
  constexpr int NLO = NREP/2;     // 2 or 1
  constexpr int LB  = BN/128;     // gloads per B-half (2 or 1)

  __shared__ __attribute__((aligned(16))) unsigned short As[2][256*64];
  __shared__ __attribute__((aligned(16))) unsigned short Bs[2][BN*64];

  const int tid = threadIdx.x;
  const int lane = tid & 63, wid = tid >> 6;
  const int wr = wid >> 2, wc = wid & 3;

  const int tile = xcd_swz(blockIdx.x, gridDim.x);
  const int tm = NMAJ ? (tile % tilesA) : (tile / tilesA);
  const int tn = NMAJ ? (tile / tilesA) : (tile % tilesA);
  const int y  = blockIdx.y;

  const unsigned short *A0 = A_, *B0 = B_;
  unsigned short* Cbp = Cb;
  float* Cfp = Cf;
  float* rsp = nullptr;
  const float* trow = nullptr;
  const float* rsd = nullptr;

  if constexpr (MODE==M_SCORE) {
    const int bl = y >> 1, d = y & 1;
    A0 = A_ + (size_t)bl*SEQ*ld + (size_t)blockIdx.z*6144 + d*1024;
    B0 = A0 + 2048;
    Cbp = Cb + ((size_t)blockIdx.z*gridDim.y + y)*SEQ*SEQ;
    rsp = Cf + ((size_t)blockIdx.z*gridDim.y + y)*SEQ;
    trow = tfb + (size_t)bl*SEQ;
  } else if constexpr (MODE==M_PV) {
    A0 = A_ + (size_t)y*SEQ*SEQ;
    B0 = B_ + (size_t)y*EMB*SEQ;
    Cbp = Cb + (size_t)(y>>1)*SEQ*2048 + (y&1)*1024;
    rsd = tfb + (size_t)y*SEQ;
  }

  const int sr = tid >> 3, ss = tid & 7;
  const int swz = (ss ^ (sr & 7)) * 8;   // pre-swizzled source col offset
  const long tmrow = (long)tm*256, tncol = (long)tn*BN;
  const int lrow = lane & 15, lks = lane >> 4;

  const unsigned short* gA = A0 + (size_t)(tmrow + sr)*ld + swz;
  const unsigned short* gB = B0 + (size_t)(tncol + sr)*ld + swz;

  f32x4 acc[8][NREP];
  #pragma unroll
  for (int m=0;m<8;++m)
    #pragma unroll
    for (int n=0;n<NREP;++n)
      #pragma unroll
      for (int r=0;r<4;++r) acc[m][n][r] = 0.f;

#define SA_H(b_, h_, t_) { \
    const long ko_ = (long)(t_)*64; \
    _Pragma("unroll") \
    for (int p=0;p<2;++p){ \
      const int p2_ = (h_)*2 + p; \
      gload16(gA + (size_t)(p2_*64)*ld + ko_, &As[b_][p2_*4096 + tid*8]); \
    } }

#define SB_H(b_, h_, t_) { \
    const long ko_ = (long)(t_)*64; \
    _Pragma("unroll") \
    for (int p=0;p<LB;++p){ \
      const int p2_ = (h_)*LB + p; \
      gload16(gB + (size_t)(p2_*64)*ld + ko_, &Bs[b_][p2_*4096 + tid*8]); \
    } }

#define LDA_F(dst, b_, mh) { \
    _Pragma("unroll") \
    for (int m=0;m<4;++m){ \
      int row_ = (m + 4*(mh))*32 + wr*16 + lrow; \
      _Pragma("unroll") \
      for (int kk=0;kk<2;++kk){ \
        int slot_ = (kk*4 + lks) ^ (row_ & 7); \
        dst[m*2+kk] = *(const bf16x8v*)&As[b_][row_*64 + slot_*8]; \
      } } }

#define LDB_F(dst, b_, nh) { \
    _Pragma("unroll") \
    for (int n=0;n<NLO;++n){ \
      int row_ = (n + NLO*(nh))*64 + wc*16 + lrow; \
      _Pragma("unroll") \
      for (int kk=0;kk<2;++kk){ \
        int slot_ = (kk*4 + lks) ^ (row_ & 7); \
        dst[n*2+kk] = *(const bf16x8v*)&Bs[b_][row_*64 + slot_*8]; \
      } } }

#define MMAC(areg, mh, bfrag, nh) { \
    __builtin_amdgcn_s_setprio(1); \
    _Pragma("unroll") \
    for (int m=0;m<4;++m) \
      _Pragma("unroll") \
      for (int n=0;n<NLO;++n) \
        _Pragma("unroll") \
        for (int kk=0;kk<2;++kk) \
          acc[(mh)*4+m][(nh)*NLO+n] = __builtin_amdgcn_mfma_f32_16x16x32_bf16( \
              areg[m*2+kk], bfrag[n*2+kk], acc[(mh)*4+m][(nh)*NLO+n], 0,0,0); \
    __builtin_amdgcn_s_setprio(0); }

#define GATEN(N_) { \
    asm volatile("s_waitcnt vmcnt(" #N_ ")" ::: "memory"); \
    __builtin_amdgcn_sched_barrier(0); \
    __builtin_amdgcn_s_barrier(); \
    __builtin_amdgcn_sched_barrier(0); }

#define SBAR() __builtin_amdgcn_sched_barrier(0);

  bf16x8v aF[8], aG[8], bL[2*NLO], bH[2*NLO];

  // prologue: stage all 4 halves of tile 0; drain A0,B0; prime aF,bL
  SA_H(0,0,0); SB_H(0,0,0); SB_H(0,1,0); SA_H(0,1,0);
  if constexpr (LB==2) { GATEN(4) } else { GATEN(3) }
  LDA_F(aF, 0, 0);
  LDB_F(bL, 0, 0);
  SBAR()

  if constexpr (SCHED==0) {
    // ---- r10 3-gate read-ahead rotation ----
    for (int t = 0; t < NT-1; ++t) {
      const int b_ = t & 1, nb_ = b_ ^ 1;
      // ph0
      SA_H(nb_,0,t+1);
      GATEN(4)                               // drains B1(t)
      LDB_F(bH, b_, 1);
      SBAR()
      MMAC(aF, 0, bL, 0);                    // q00
      // ph1
      SB_H(nb_,0,t+1);
      if constexpr (LB==2) { GATEN(4) } else { GATEN(3) }  // drains A1(t)
      MMAC(aF, 0, bH, 1);                    // q01
      LDA_F(aF, b_, 1);
      SBAR()
      // ph2 (no gate)
      SB_H(nb_,1,t+1);
      MMAC(aF, 1, bH, 1);                    // q11
      // ph3
      SA_H(nb_,1,t+1);
      if constexpr (LB==2) { GATEN(4) } else { GATEN(3) }  // drains A0,B0(t+1)
      MMAC(aF, 1, bL, 0);                    // q10
      LDA_F(aF, nb_, 0);
      LDB_F(bL, nb_, 0);
      SBAR()
    }
    { // peeled last tile
      const int b_ = (NT-1) & 1;
      GATEN(2)                               // drains B1(last)
      LDB_F(bH, b_, 1);
      SBAR()
      MMAC(aF, 0, bL, 0);
      GATEN(0)                               // drains A1(last)
      MMAC(aF, 0, bH, 1);
      LDA_F(aF, b_, 1);
      SBAR()
      MMAC(aF, 1, bH, 1);
      MMAC(aF, 1, bL, 0);
    }
  } else {
    // ---- r15 2-gate dual-A ----
    for (int t = 0; t < NT-1; ++t) {
      const int b_ = t & 1, nb_ = b_ ^ 1;
      SA_H(nb_,0,t+1);
      SB_H(nb_,0,t+1);
      if constexpr (LB==2) { GATEN(4) } else { GATEN(3) }  // drains {B1,A1}(t)
      LDB_F(bH, b_, 1);
      LDA_F(aG, b_, 1);
      SBAR()
      MMAC(aF, 0, bL, 0);
      MMAC(aF, 0, bH, 1);
      MMAC(aG, 1, bH, 1);
      MMAC(aG, 1, bL, 0);
      SB_H(nb_,1,t+1);
      SA_H(nb_,1,t+1);
      if constexpr (LB==2) { GATEN(4) } else { GATEN(3) }  // drains {A0,B0}(t+1)
      LDA_F(aF, nb_, 0);
      LDB_F(bL, nb_, 0);
      SBAR()
    }
    { // peeled last tile
      const int b_ = (NT-1) & 1;
      GATEN(0)
      LDB_F(bH, b_, 1);
      LDA_F(aG, b_, 1);
      SBAR()
      MMAC(aF, 0, bL, 0);
      MMAC(aF, 0, bH, 1);
      MMAC(aG, 1, bH, 1);
      MMAC(aG, 1, bL, 0);
    }
  }

  // epilogue: C/D layout col = lane&15, row = (lane>>4)*4 + reg
  const int rr = (lane >> 4) * 4, cc = lane & 15;

  if constexpr (MODE==M_SCORE) {
    float cm[NREP];
    #pragma unroll
    for (int n=0;n<NREP;++n) cm[n] = 0.03125f * trow[tncol + n*64 + wc*16 + cc];
    #pragma unroll
    for (int m=0;m<8;++m)
      #pragma unroll
      for (int n=0;n<NREP;++n)
        #pragma unroll
        for (int r=0;r<4;++r)
          acc[m][n][r] = __expf(acc[m][n][r] * cm[n]);
    #pragma unroll
    for (int n=0;n<NREP;++n){
      const long col = tncol + n*64 + wc*16 + cc;
      #pragma unroll
      for (int m=0;m<8;++m){
        const long row = tmrow + m*32 + wr*16 + rr;
        #pragma unroll
        for (int r=0;r<4;++r)
          Cbp[(row + r)*(size_t)ldc + col] = f2bf(acc[m][n][r]);
      }
    }
    #pragma unroll
    for (int m=0;m<8;++m){
      #pragma unroll
      for (int r=0;r<4;++r){
        float s = 0.f;
        #pragma unroll
        for (int n=0;n<NREP;++n) s += acc[m][n][r];
        s += __shfl_xor(s, 1); s += __shfl_xor(s, 2);
        s += __shfl_xor(s, 4); s += __shfl_xor(s, 8);
        if ((lane & 15) == 0)
          atomicAdd(&rsp[tmrow + m*32 + wr*16 + rr + r], s);
      }
    }
  } else if constexpr (MODE==M_PV) {
    #pragma unroll
    for (int m=0;m<8;++m){
      const long row0 = tmrow + m*32 + wr*16 + rr;
      float4 rsv = *(const float4*)&rsd[row0];
      float inv[4];
      inv[0] = 1.f/rsv.x; inv[1] = 1.f/rsv.y; inv[2] = 1.f/rsv.z; inv[3] = 1.f/rsv.w;
      #pragma unroll
      for (int n=0;n<NREP;++n){
        const long col = tncol + n*64 + wc*16 + cc;
        #pragma unroll
        for (int r=0;r<4;++r){
          size_t idx = (row0 + r)*(size_t)ldc + col;
          float w = acc[m][n][r]*inv[r] + (accflag ? bf2f(Cbp[idx]) : 0.f);
          Cbp[idx] = f2bf(w);
        }
      }
    }
  } else if constexpr (MODE==M_LIN) {
    const bool vt_tile = (vtp != nullptr) && ((tncol % 6144) >= 4096);
    if (vt_tile) {
      // write V transposed: VT[yo][e][t], yo = dir*2*nbl + bl*2 + d
      const int dir = (int)(tncol / 6144);
      const int bl  = (int)(tmrow >> 11);
      const long vrel0 = (tncol % 6144) - 4096;
      unsigned short* vbase = vtp + (size_t)dir*nbl*2*EMB*SEQ;
      #pragma unroll
      for (int n=0;n<NREP;++n){
        const long col = tncol + n*64 + wc*16 + cc;
        const float cadd = bias[col];
        const long ef = vrel0 + n*64 + wc*16 + cc;   // 0..2047
        const int d = (int)(ef >> 10);
        const long e = ef & 1023;
        unsigned short* vrow = vbase + ((size_t)(bl*2 + d)*EMB + e)*SEQ;
        #pragma unroll
        for (int m=0;m<8;++m){
          const long t0 = tmrow + m*32 + wr*16 + rr;
          u16x4 o;
          #pragma unroll
          for (int r=0;r<4;++r) o[r] = f2bf(acc[m][n][r] + cadd);
          *(u16x4*)&vrow[(t0 & 2047)] = o;
        }
      }
    } else {
      #pragma unroll
      for (int n=0;n<NREP;++n){
        const long col = tncol + n*64 + wc*16 + cc;
        const float cadd = bias[col];
        #pragma unroll
        for (int m=0;m<8;++m){
          const long row = tmrow + m*32 + wr*16 + rr;
          #pragma unroll
          for (int r=0;r<4;++r)
            Cbp[(row + r)*(size_t)ldc + col] = f2bf(acc[m][n][r] + cadd);
        }
      }
    }
  } else { // M_OUT
    #pragma unroll
    for (int n=0;n<NREP;++n){
      const long col = tncol + n*64 + wc*16 + cc;
      const float cadd = bias[col];
      #pragma unroll
      for (int m=0;m<8;++m){
        const long row = tmrow + m*32 + wr*16 + rr;
        #pragma unroll
        for (int r=0;r<4;++r)
          Cfp[(row + r)*(size_t)ldc + col] = acc[m][n][r] + cadd;
      }
    }
  }
#undef SA_H
#undef SB_H
#undef LDA_F
#undef LDB_F
#undef MMAC
#undef GATEN
#undef SBAR
}

// ---------------- V transpose (fallback tiers only) ----------------
__global__ __launch_bounds__(256) void k_transpose_v(const unsigned short* __restrict__ Vsrc,
                                                     unsigned short* __restrict__ VT, int ld){
  __shared__ unsigned short tile[64][72];
  int yo = blockIdx.z*gridDim.y + blockIdx.y;
  int bl = blockIdx.y >> 1, d = blockIdx.y & 1;
  int tt = (blockIdx.x & 31) * 64;
  int te = (blockIdx.x >> 5) * 64;
  const unsigned short* src = Vsrc + (size_t)bl*SEQ*ld + (size_t)blockIdx.z*6144 + d*1024;
  int tid = threadIdx.x;
  #pragma unroll
  for (int it=0; it<2; ++it){
    int c = it*256 + tid;
    int r = c >> 3, c8 = (c & 7) * 8;
    u16x8 v = *(const u16x8*)&src[(size_t)(tt + r)*ld + te + c8];
    *(u16x8*)&tile[r][c8] = v;
  }
  __syncthreads();
  #pragma unroll
  for (int it=0; it<2; ++it){
    int c = it*256 + tid;
    int re = c >> 3, c8 = (c & 7) * 8;
    u16x8 o;
    #pragma unroll
    for (int j=0;j<8;++j) o[j] = tile[c8 + j][re];
    *(u16x8*)&VT[((size_t)yo*EMB + te + re)*SEQ + tt + c8] = o;
  }
}

// ---------------- launch ----------------
extern "C" void kernel_launch(void* const* d_in, const int* in_sizes, int n_in,
                              void* d_out, int out_size, void* d_ws, size_t ws_size,
                              hipStream_t stream){
  const float* x  = (const float*)d_in[0];
  const float* tf = (const float*)d_in[1];
  const float* W[6]; const float* bz[6];
  for (int i=0;i<6;++i){ W[i]=(const float*)d_in[2+2*i]; bz[i]=(const float*)d_in[3+2*i]; }
  const float* Wo = (const float*)d_in[14];
  const float* bo = (const float*)d_in[15];
  float* outp = (float*)d_out;

  auto al = [](size_t b){ return (b + 255) & ~(size_t)255; };
  const size_t SZ_XB   = (size_t)8192*1024*2;
  const size_t SZ_WCAT = (size_t)12288*1024*2;
  const size_t SZ_WOB  = (size_t)1024*2048*2;
  const size_t SZ_BCAT = (size_t)12288*4;
  const size_t SZ_AO   = (size_t)8192*2048*2;
  const size_t fixedB  = al(SZ_XB)+al(SZ_WCAT)+al(SZ_WOB)+al(SZ_BCAT)+al(SZ_AO);

  auto chB = [&](int CB, bool merged, bool both)->size_t {
    int nd = both ? 2 : 1;
    return al((size_t)CB*SEQ*(merged?12288:6144)*2)
         + al((size_t)nd*CB*2*SEQ*SEQ*2)
         + al((size_t)nd*CB*2*EMB*SEQ*2)
         + al((size_t)nd*CB*2*SEQ*4);
  };
  int CB; bool merged, both;
  if      (ws_size >= fixedB + chB(4,true ,true )) { CB=4; merged=true;  both=true;  }
  else if (ws_size >= fixedB + chB(2,true ,true )) { CB=2; merged=true;  both=true;  }
  else if (ws_size >= fixedB + chB(2,true ,false)) { CB=2; merged=true;  both=false; }
  else if (ws_size >= fixedB + chB(2,false,false)) { CB=2; merged=false; both=false; }
  else if (ws_size >= fixedB + chB(1,false,false)) { CB=1; merged=false; both=false; }
  else return;
  const int ldY = merged ? 12288 : 6144;
  const int nd = both ? 2 : 1;

  char* ws = (char*)d_ws; size_t off = 0;
  auto take = [&](size_t bytes)->char* { char* p = ws + off; off += al(bytes); return p; };
  unsigned short* xb   = (unsigned short*)take(SZ_XB);
  unsigned short* Wcat = (unsigned short*)take(SZ_WCAT);
  unsigned short* WoB  = (unsigned short*)take(SZ_WOB);
  float*          bcat = (float*)take(SZ_BCAT);
  unsigned short* AO   = (unsigned short*)take(SZ_AO);
  unsigned short* Ych  = (unsigned short*)take((size_t)CB*SEQ*ldY*2);
  const size_t scHalf = (size_t)CB*2*SEQ*SEQ;
  const size_t vtHalf = (size_t)CB*2*EMB*SEQ;
  const size_t rsHalf = (size_t)CB*2*SEQ;
  unsigned short* Sc = (unsigned short*)take(nd*scHalf*2);
  unsigned short* VT = (unsigned short*)take(nd*vtHalf*2);
  float*          rs = (float*)take(nd*rsHalf*4);

  k_cvt_bf16   <<<8192, 256, 0, stream>>>(x, xb, 2097152);
  k_build_wcat <<<12288,256, 0, stream>>>(W[0],W[1],W[2],W[3],W[4],W[5], Wcat);
  k_cvt_bf16   <<<2048, 256, 0, stream>>>(Wo, WoB, 524288);
  k_build_bcat <<<48,   256, 0, stream>>>(bz[0],bz[1],bz[2],bz[3],bz[4],bz[5], bcat);

  for (int c = 0; c < 4/CB; ++c) {
    const int b0 = c*CB;
    const unsigned short* xchunk = xb + (size_t)b0*SEQ*1024;
    if (merged) {
      gemm4p<M_LIN,256,1,0><<<dim3(CB*8*48, 1), 512, 0, stream>>>(
          xchunk, Wcat, Ych, nullptr, bcat, nullptr,
          both ? VT : nullptr, CB, 1024, 12288, CB*8, 0);
    }
    if (both) {
      hipMemsetAsync(rs, 0, 2*rsHalf*4, stream);
      gemm4p<M_SCORE,256,0,1><<<dim3(64, 2*CB, 2), 512, 0, stream>>>(
          Ych, nullptr, Sc, rs, nullptr, tf + (size_t)b0*SEQ,
          nullptr, 0, ldY, 2048, 8, 0);
      for (int dir = 0; dir < 2; ++dir) {
        gemm4p<M_PV,128,0,1><<<dim3(64, 2*CB), 512, 0, stream>>>(
            Sc + dir*scHalf, VT + dir*vtHalf, AO + (size_t)b0*SEQ*2048, nullptr,
            nullptr, rs + dir*rsHalf, nullptr, 0, 2048, 2048, 8, dir);
      }
    } else {
      for (int dir = 0; dir < 2; ++dir) {
        const unsigned short* Ybase = Ych + (merged ? dir*6144 : 0);
        if (!merged) {
          gemm4p<M_LIN,256,1,0><<<dim3(CB*8*24, 1), 512, 0, stream>>>(
              xchunk, Wcat + (size_t)dir*6144*1024, Ych, nullptr,
              bcat + dir*6144, nullptr, nullptr, 0, 1024, 6144, CB*8, 0);
        }
        hipMemsetAsync(rs, 0, rsHalf*4, stream);
        gemm4p<M_SCORE,256,0,1><<<dim3(64, 2*CB, 1), 512, 0, stream>>>(
            Ybase, nullptr, Sc, rs, nullptr, tf + (size_t)b0*SEQ,
            nullptr, 0, ldY, 2048, 8, 0);
        k_transpose_v<<<dim3(512, 2*CB, 1), 256, 0, stream>>>(Ybase + 4096, VT, ldY);
        gemm4p<M_PV,128,0,1><<<dim3(64, 2*CB), 512, 0, stream>>>(
            Sc, VT, AO + (size_t)b0*SEQ*2048, nullptr,
            nullptr, rs, nullptr, 0, 2048, 2048, 8, dir);
      }
    }
  }
  // out = AO @ Wo^T + bo  — N-major, grid 256, tilesM=32
  gemm4p<M_OUT,128,1,1><<<dim3(256, 1), 512, 0, stream>>>(
      AO, WoB, nullptr, outp, bo, nullptr, nullptr, 0, 2048, 1024, 32, 0);
}

// Round 18
// 705.120 us; speedup vs baseline: 1.0420x; 1.0420x over previous
//
#include <hip/hip_runtime.h>
#include <hip/hip_bf16.h>
#include <stdint.h>

#define SEQ 2048
#define EMB 1024

typedef __attribute__((ext_vector_type(4))) float f32x4;
typedef __attribute__((ext_vector_type(8))) __bf16 bf16x8v;
typedef __attribute__((ext_vector_type(8))) unsigned short u16x8;
typedef __attribute__((ext_vector_type(4))) unsigned short u16x4;

static __device__ __forceinline__ float bf2f(unsigned short u){
  union { unsigned int i; float f; } v; v.i = ((unsigned int)u) << 16; return v.f;
}
static __device__ __forceinline__ unsigned short f2bf(float f){
  union { float f; unsigned int i; } v; v.f = f;
  unsigned int r = v.i + 0x7FFFu + ((v.i >> 16) & 1u);
  return (unsigned short)(r >> 16);
}

static __device__ __forceinline__ void gload16(const unsigned short* g, unsigned short* l){
  __builtin_amdgcn_global_load_lds(
      (__attribute__((address_space(1))) unsigned int*)(g),
      (__attribute__((address_space(3))) unsigned int*)(l), 16, 0, 0);
}

// XCD-aware tile swizzle (valid when nwg % 8 == 0)
static __device__ __forceinline__ int xcd_swz(int bid, int nwg){
  int q = nwg >> 3;
  return (bid & 7) * q + (bid >> 3);
}

// ---------------- converters ----------------
__global__ __launch_bounds__(256) void k_cvt_bf16(const float* __restrict__ in,
                                                  unsigned short* __restrict__ out, long n4){
  long i = (long)blockIdx.x * 256 + threadIdx.x;
  if (i >= n4) return;
  float4 v = ((const float4*)in)[i];
  u16x4 o; o.x = f2bf(v.x); o.y = f2bf(v.y); o.z = f2bf(v.z); o.w = f2bf(v.w);
  ((u16x4*)out)[i] = o;
}

__global__ __launch_bounds__(256) void k_build_wcat(
    const float* __restrict__ w0, const float* __restrict__ w1,
    const float* __restrict__ w2, const float* __restrict__ w3,
    const float* __restrict__ w4, const float* __restrict__ w5,
    unsigned short* __restrict__ wcat){
  long i = (long)blockIdx.x * 256 + threadIdx.x;
  long g = i * 4;
  int m = (int)(g >> 21);
  const float* src = (m==0)?w0:(m==1)?w1:(m==2)?w2:(m==3)?w3:(m==4)?w4:w5;
  long loc = g & ((1L<<21)-1);
  float4 v = *(const float4*)&src[loc];
  u16x4 o; o.x=f2bf(v.x); o.y=f2bf(v.y); o.z=f2bf(v.z); o.w=f2bf(v.w);
  *(u16x4*)&wcat[g] = o;
}

__global__ __launch_bounds__(256) void k_build_bcat(
    const float* b0, const float* b1, const float* b2,
    const float* b3, const float* b4, const float* b5, float* __restrict__ bcat){
  int i = blockIdx.x * 256 + threadIdx.x;
  int m = i >> 11;
  const float* src = (m==0)?b0:(m==1)?b1:(m==2)?b2:(m==3)?b3:(m==4)?b4:b5;
  bcat[i] = src[i & 2047];
}

#define M_LIN   0
#define M_SCORE 1
#define M_PV    2
#define M_OUT   3

// ====== 256xBN GEMM (C = A @ B^T), 512 thr / 8 waves (2M x 4N) ======
// r10-proven half-tile pipeline with READ-AHEAD rotation (best: 39.5% MfmaUtil).
// M_SCORE: epilogue computes E=exp(s*tfidf/32) (no max-sub; scores ~N(0,1)),
//   writes bf16 E, and atomicAdds per-row partial sums into rs[] (Cf slot).
//   blockIdx.z selects direction (A dir offset +z*6144; Sc/rs slot z*gridDim.y+y).
// M_PV: epilogue divides acc by rs[row] (tfb slot = per-head rowsum base),
//   then writes (accflag=0) or RMW-adds (accflag=1) into AO.
template<int MODE, int BN>
__global__ __launch_bounds__(512, 2)
void gemm4p(const unsigned short* __restrict__ A_,
            const unsigned short* __restrict__ B_,
            unsigned short* __restrict__ Cb, float* __restrict__ Cf,
            const float* __restrict__ bias, const float* __restrict__ tfb,
            int ld, int ldc, int tilesN, int accflag)
{
  constexpr int KD  = (MODE==M_PV || MODE==M_OUT) ? 2048 : 1024;
  constexpr int NT  = KD/64;
  constexpr int NREP= BN/64;      // 4 or 2
  constexpr int NLO = NREP/2;     // 2 or 1
  constexpr int LB  = BN/128;     // gloads per B-half (2 or 1)

  __shared__ __attribute__((aligned(16))) unsigned short As[2][256*64];
  __shared__ __attribute__((aligned(16))) unsigned short Bs[2][BN*64];

  const int tid = threadIdx.x;
  const int lane = tid & 63, wid = tid >> 6;
  const int wr = wid >> 2, wc = wid & 3;

  const int tile = xcd_swz(blockIdx.x, gridDim.x);
  const int tm = tile / tilesN, tn = tile % tilesN;
  const int y  = blockIdx.y;

  const unsigned short *A0 = A_, *B0 = B_;
  unsigned short* Cbp = Cb;
  float* Cfp = Cf;
  float* rsp = nullptr;
  const float* trow = nullptr;
  const float* rsd = nullptr;

  if constexpr (MODE==M_SCORE) {
    const int bl = y >> 1, d = y & 1;
    A0 = A_ + (size_t)bl*SEQ*ld + (size_t)blockIdx.z*6144 + d*1024;
    B0 = A0 + 2048;
    Cbp = Cb + ((size_t)blockIdx.z*gridDim.y + y)*SEQ*SEQ;
    rsp = Cf + ((size_t)blockIdx.z*gridDim.y + y)*SEQ;
    trow = tfb + (size_t)bl*SEQ;
  } else if constexpr (MODE==M_PV) {
    A0 = A_ + (size_t)y*SEQ*SEQ;
    B0 = B_ + (size_t)y*EMB*SEQ;
    Cbp = Cb + (size_t)(y>>1)*SEQ*2048 + (y&1)*1024;
    rsd = tfb + (size_t)y*SEQ;
  }

  const int sr = tid >> 3, ss = tid & 7;
  const int swz = (ss ^ (sr & 7)) * 8;   // pre-swizzled source col offset
  const long tmrow = (long)tm*256, tncol = (long)tn*BN;
  const int lrow = lane & 15, lks = lane >> 4;

  const unsigned short* gA = A0 + (size_t)(tmrow + sr)*ld + swz;
  const unsigned short* gB = B0 + (size_t)(tncol + sr)*ld + swz;

  f32x4 acc[8][NREP];
  #pragma unroll
  for (int m=0;m<8;++m)
    #pragma unroll
    for (int n=0;n<NREP;++n)
      #pragma unroll
      for (int r=0;r<4;++r) acc[m][n][r] = 0.f;

#define SA_H(b_, h_, t_) { \
    const long ko_ = (long)(t_)*64; \
    _Pragma("unroll") \
    for (int p=0;p<2;++p){ \
      const int p2_ = (h_)*2 + p; \
      gload16(gA + (size_t)(p2_*64)*ld + ko_, &As[b_][p2_*4096 + tid*8]); \
    } }

#define SB_H(b_, h_, t_) { \
    const long ko_ = (long)(t_)*64; \
    _Pragma("unroll") \
    for (int p=0;p<LB;++p){ \
      const int p2_ = (h_)*LB + p; \
      gload16(gB + (size_t)(p2_*64)*ld + ko_, &Bs[b_][p2_*4096 + tid*8]); \
    } }

#define LDA_F(dst, b_, mh) { \
    _Pragma("unroll") \
    for (int m=0;m<4;++m){ \
      int row_ = (m + 4*(mh))*32 + wr*16 + lrow; \
      _Pragma("unroll") \
      for (int kk=0;kk<2;++kk){ \
        int slot_ = (kk*4 + lks) ^ (row_ & 7); \
        dst[m*2+kk] = *(const bf16x8v*)&As[b_][row_*64 + slot_*8]; \
      } } }

#define LDB_F(dst, b_, nh) { \
    _Pragma("unroll") \
    for (int n=0;n<NLO;++n){ \
      int row_ = (n + NLO*(nh))*64 + wc*16 + lrow; \
      _Pragma("unroll") \
      for (int kk=0;kk<2;++kk){ \
        int slot_ = (kk*4 + lks) ^ (row_ & 7); \
        dst[n*2+kk] = *(const bf16x8v*)&Bs[b_][row_*64 + slot_*8]; \
      } } }

#define MMAC(mh, bfrag, nh) { \
    __builtin_amdgcn_s_setprio(1); \
    _Pragma("unroll") \
    for (int m=0;m<4;++m) \
      _Pragma("unroll") \
      for (int n=0;n<NLO;++n) \
        _Pragma("unroll") \
        for (int kk=0;kk<2;++kk) \
          acc[(mh)*4+m][(nh)*NLO+n] = __builtin_amdgcn_mfma_f32_16x16x32_bf16( \
              aF[m*2+kk], bfrag[n*2+kk], acc[(mh)*4+m][(nh)*NLO+n], 0,0,0); \
    __builtin_amdgcn_s_setprio(0); }

#define GATEN(N_) { \
    asm volatile("s_waitcnt vmcnt(" #N_ ")" ::: "memory"); \
    __builtin_amdgcn_sched_barrier(0); \
    __builtin_amdgcn_s_barrier(); \
    __builtin_amdgcn_sched_barrier(0); }

#define SBAR() __builtin_amdgcn_sched_barrier(0);

  bf16x8v aF[8], bL[2*NLO], bH[2*NLO];

  // prologue: tile 0, issue order A0,B0,B1,A1; prime aF,bL
  SA_H(0,0,0); SB_H(0,0,0); SB_H(0,1,0); SA_H(0,1,0);
  if constexpr (LB==2) { GATEN(4) } else { GATEN(3) }   // A0,B0(0) landed
  LDA_F(aF, 0, 0);
  LDB_F(bL, 0, 0);
  SBAR()

  for (int t = 0; t < NT-1; ++t) {
    const int b_ = t & 1, nb_ = b_ ^ 1;
    // ---- ph0 ----
    SA_H(nb_,0,t+1);
    GATEN(4)                               // drains B1(t)
    LDB_F(bH, b_, 1);                      // read-ahead for ph1
    SBAR()
    MMAC(0, bL, 0);                        // q00: A0*B0
    // ---- ph1 ----
    SB_H(nb_,0,t+1);
    if constexpr (LB==2) { GATEN(4) } else { GATEN(3) }  // drains A1(t)
    MMAC(0, bH, 1);                        // q01: A0*B1
    LDA_F(aF, b_, 1);                      // aF <- A1(t) (A0 dead)
    SBAR()
    // ---- ph2 (no gate) ----
    SB_H(nb_,1,t+1);
    MMAC(1, bH, 1);                        // q11: A1*B1
    // ---- ph3 ----
    SA_H(nb_,1,t+1);
    if constexpr (LB==2) { GATEN(4) } else { GATEN(3) }  // drains A0,B0(t+1)
    MMAC(1, bL, 0);                        // q10: A1*B0
    LDA_F(aF, nb_, 0);                     // aF <- A0(t+1)
    LDB_F(bL, nb_, 0);                     // bL <- B0(t+1)
    SBAR()
  }

  { // peeled last tile: exact drains, no staging
    const int b_ = (NT-1) & 1;
    GATEN(2)                               // drains B1(last)
    LDB_F(bH, b_, 1);
    SBAR()
    MMAC(0, bL, 0);
    GATEN(0)                               // drains A1(last)
    MMAC(0, bH, 1);
    LDA_F(aF, b_, 1);
    SBAR()
    MMAC(1, bH, 1);
    MMAC(1, bL, 0);
  }

  // epilogue: C/D layout col = lane&15, row = (lane>>4)*4 + reg
  const int rr = (lane >> 4) * 4, cc = lane & 15;

  if constexpr (MODE==M_SCORE) {
    // E = exp(score * tfidf/32); store bf16; atomic row-sum into rsp.
    float cm[NREP];
    #pragma unroll
    for (int n=0;n<NREP;++n) cm[n] = 0.03125f * trow[tncol + n*64 + wc*16 + cc];
    #pragma unroll
    for (int m=0;m<8;++m)
      #pragma unroll
      for (int n=0;n<NREP;++n)
        #pragma unroll
        for (int r=0;r<4;++r)
          acc[m][n][r] = __expf(acc[m][n][r] * cm[n]);
    #pragma unroll
    for (int n=0;n<NREP;++n){
      const long col = tncol + n*64 + wc*16 + cc;
      #pragma unroll
      for (int m=0;m<8;++m){
        const long row = tmrow + m*32 + wr*16 + rr;
        #pragma unroll
        for (int r=0;r<4;++r)
          Cbp[(row + r)*(size_t)ldc + col] = f2bf(acc[m][n][r]);
      }
    }
    #pragma unroll
    for (int m=0;m<8;++m){
      #pragma unroll
      for (int r=0;r<4;++r){
        float s = 0.f;
        #pragma unroll
        for (int n=0;n<NREP;++n) s += acc[m][n][r];
        s += __shfl_xor(s, 1); s += __shfl_xor(s, 2);
        s += __shfl_xor(s, 4); s += __shfl_xor(s, 8);
        if ((lane & 15) == 0)
          atomicAdd(&rsp[tmrow + m*32 + wr*16 + rr + r], s);
      }
    }
  } else if constexpr (MODE==M_PV) {
    #pragma unroll
    for (int m=0;m<8;++m){
      const long row0 = tmrow + m*32 + wr*16 + rr;
      float4 rsv = *(const float4*)&rsd[row0];
      float inv[4];
      inv[0] = 1.f/rsv.x; inv[1] = 1.f/rsv.y; inv[2] = 1.f/rsv.z; inv[3] = 1.f/rsv.w;
      #pragma unroll
      for (int n=0;n<NREP;++n){
        const long col = tncol + n*64 + wc*16 + cc;
        #pragma unroll
        for (int r=0;r<4;++r){
          size_t idx = (row0 + r)*(size_t)ldc + col;
          float w = acc[m][n][r]*inv[r] + (accflag ? bf2f(Cbp[idx]) : 0.f);
          Cbp[idx] = f2bf(w);
        }
      }
    }
  } else {
    #pragma unroll
    for (int n=0;n<NREP;++n){
      const long col = tncol + n*64 + wc*16 + cc;
      const float cadd = bias[col];
      #pragma unroll
      for (int m=0;m<8;++m){
        const long row = tmrow + m*32 + wr*16 + rr;
        #pragma unroll
        for (int r=0;r<4;++r){
          float v = acc[m][n][r] + cadd;
          if constexpr (MODE==M_OUT) Cfp[(row + r)*(size_t)ldc + col] = v;
          else                       Cbp[(row + r)*(size_t)ldc + col] = f2bf(v);
        }
      }
    }
  }
#undef SA_H
#undef SB_H
#undef LDA_F
#undef LDB_F
#undef MMAC
#undef GATEN
#undef SBAR
}

// ---------------- V transpose: VT[z*H+y][e][t] ----------------
__global__ __launch_bounds__(256) void k_transpose_v(const unsigned short* __restrict__ Vsrc,
                                                     unsigned short* __restrict__ VT, int ld){
  __shared__ unsigned short tile[64][72];
  int yo = blockIdx.z*gridDim.y + blockIdx.y;
  int bl = blockIdx.y >> 1, d = blockIdx.y & 1;
  int tt = (blockIdx.x & 31) * 64;
  int te = (blockIdx.x >> 5) * 64;
  const unsigned short* src = Vsrc + (size_t)bl*SEQ*ld + (size_t)blockIdx.z*6144 + d*1024;
  int tid = threadIdx.x;
  #pragma unroll
  for (int it=0; it<2; ++it){
    int c = it*256 + tid;
    int r = c >> 3, c8 = (c & 7) * 8;
    u16x8 v = *(const u16x8*)&src[(size_t)(tt + r)*ld + te + c8];
    *(u16x8*)&tile[r][c8] = v;
  }
  __syncthreads();
  #pragma unroll
  for (int it=0; it<2; ++it){
    int c = it*256 + tid;
    int re = c >> 3, c8 = (c & 7) * 8;
    u16x8 o;
    #pragma unroll
    for (int j=0;j<8;++j) o[j] = tile[c8 + j][re];
    *(u16x8*)&VT[((size_t)yo*EMB + te + re)*SEQ + tt + c8] = o;
  }
}

// ---------------- launch ----------------
extern "C" void kernel_launch(void* const* d_in, const int* in_sizes, int n_in,
                              void* d_out, int out_size, void* d_ws, size_t ws_size,
                              hipStream_t stream){
  const float* x  = (const float*)d_in[0];
  const float* tf = (const float*)d_in[1];
  const float* W[6]; const float* bz[6];
  for (int i=0;i<6;++i){ W[i]=(const float*)d_in[2+2*i]; bz[i]=(const float*)d_in[3+2*i]; }
  const float* Wo = (const float*)d_in[14];
  const float* bo = (const float*)d_in[15];
  float* outp = (float*)d_out;

  auto al = [](size_t b){ return (b + 255) & ~(size_t)255; };
  const size_t SZ_XB   = (size_t)8192*1024*2;
  const size_t SZ_WCAT = (size_t)12288*1024*2;
  const size_t SZ_WOB  = (size_t)1024*2048*2;
  const size_t SZ_BCAT = (size_t)12288*4;
  const size_t SZ_AO   = (size_t)8192*2048*2;
  const size_t fixedB  = al(SZ_XB)+al(SZ_WCAT)+al(SZ_WOB)+al(SZ_BCAT)+al(SZ_AO);

  // per-chunk sizes: Ych, Sc, VT, rs (ndirs = 2 if both-dirs buffers held)
  auto chB = [&](int CB, bool merged, bool both)->size_t {
    int nd = both ? 2 : 1;
    return al((size_t)CB*SEQ*(merged?12288:6144)*2)         // Ych
         + al((size_t)nd*CB*2*SEQ*SEQ*2)                    // Sc (E)
         + al((size_t)nd*CB*2*EMB*SEQ*2)                    // VT
         + al((size_t)nd*CB*2*SEQ*4);                       // rs
  };
  int CB; bool merged, both;
  if      (ws_size >= fixedB + chB(4,true ,true )) { CB=4; merged=true;  both=true;  }
  else if (ws_size >= fixedB + chB(2,true ,true )) { CB=2; merged=true;  both=true;  }
  else if (ws_size >= fixedB + chB(2,true ,false)) { CB=2; merged=true;  both=false; }
  else if (ws_size >= fixedB + chB(2,false,false)) { CB=2; merged=false; both=false; }
  else if (ws_size >= fixedB + chB(1,false,false)) { CB=1; merged=false; both=false; }
  else return;
  const int ldY = merged ? 12288 : 6144;
  const int nd = both ? 2 : 1;

  char* ws = (char*)d_ws; size_t off = 0;
  auto take = [&](size_t bytes)->char* { char* p = ws + off; off += al(bytes); return p; };
  unsigned short* xb   = (unsigned short*)take(SZ_XB);
  unsigned short* Wcat = (unsigned short*)take(SZ_WCAT);
  unsigned short* WoB  = (unsigned short*)take(SZ_WOB);
  float*          bcat = (float*)take(SZ_BCAT);
  unsigned short* AO   = (unsigned short*)take(SZ_AO);
  unsigned short* Ych  = (unsigned short*)take((size_t)CB*SEQ*ldY*2);
  const size_t scHalf = (size_t)CB*2*SEQ*SEQ;   // elements per dir
  const size_t vtHalf = (size_t)CB*2*EMB*SEQ;
  const size_t rsHalf = (size_t)CB*2*SEQ;
  unsigned short* Sc = (unsigned short*)take(nd*scHalf*2);
  unsigned short* VT = (unsigned short*)take(nd*vtHalf*2);
  float*          rs = (float*)take(nd*rsHalf*4);

  k_cvt_bf16   <<<8192, 256, 0, stream>>>(x, xb, 2097152);
  k_build_wcat <<<12288,256, 0, stream>>>(W[0],W[1],W[2],W[3],W[4],W[5], Wcat);
  k_cvt_bf16   <<<2048, 256, 0, stream>>>(Wo, WoB, 524288);
  k_build_bcat <<<48,   256, 0, stream>>>(bz[0],bz[1],bz[2],bz[3],bz[4],bz[5], bcat);

  for (int c = 0; c < 4/CB; ++c) {
    const int b0 = c*CB;
    const unsigned short* xchunk = xb + (size_t)b0*SEQ*1024;
    if (merged) {
      gemm4p<M_LIN,256><<<dim3(CB*8*48, 1), 512, 0, stream>>>(
          xchunk, Wcat, Ych, nullptr, bcat, nullptr, 1024, 12288, 48, 0);
    }
    if (both) {
      // SCORE + transpose for BOTH dirs in one dispatch each
      hipMemsetAsync(rs, 0, 2*rsHalf*4, stream);
      gemm4p<M_SCORE,256><<<dim3(64, 2*CB, 2), 512, 0, stream>>>(
          Ych, nullptr, Sc, rs, nullptr, tf + (size_t)b0*SEQ, ldY, 2048, 8, 0);
      k_transpose_v<<<dim3(512, 2*CB, 2), 256, 0, stream>>>(Ych + 4096, VT, ldY);
      for (int dir = 0; dir < 2; ++dir) {
        gemm4p<M_PV,128><<<dim3(64, 2*CB), 512, 0, stream>>>(
            Sc + dir*scHalf, VT + dir*vtHalf, AO + (size_t)b0*SEQ*2048, nullptr,
            nullptr, rs + dir*rsHalf, 2048, 2048, 8, dir);
      }
    } else {
      for (int dir = 0; dir < 2; ++dir) {
        const unsigned short* Ybase = Ych + (merged ? dir*6144 : 0);
        if (!merged) {
          gemm4p<M_LIN,256><<<dim3(CB*8*24, 1), 512, 0, stream>>>(
              xchunk, Wcat + (size_t)dir*6144*1024, Ych, nullptr,
              bcat + dir*6144, nullptr, 1024, 6144, 24, 0);
        }
        hipMemsetAsync(rs, 0, rsHalf*4, stream);
        gemm4p<M_SCORE,256><<<dim3(64, 2*CB, 1), 512, 0, stream>>>(
            Ybase, nullptr, Sc, rs, nullptr, tf + (size_t)b0*SEQ, ldY, 2048, 8, 0);
        k_transpose_v<<<dim3(512, 2*CB, 1), 256, 0, stream>>>(Ybase + 4096, VT, ldY);
        gemm4p<M_PV,128><<<dim3(64, 2*CB), 512, 0, stream>>>(
            Sc, VT, AO + (size_t)b0*SEQ*2048, nullptr,
            nullptr, rs, 2048, 2048, 8, dir);
      }
    }
  }
  // out = AO @ Wo^T + bo   ([8192,1024], K=2048, f32) — one dispatch
  gemm4p<M_OUT,128><<<dim3(256, 1), 512, 0, stream>>>(
      AO, WoB, nullptr, outp, bo, nullptr, 2048, 1024, 8, 0);
}